// Round 6
// baseline (94.876 us; speedup 1.0000x reference)
//
#include <hip/hip_runtime.h>
#include <hip/hip_bf16.h>
#include <hip/hip_cooperative_groups.h>

namespace cg = cooperative_groups;

#define C_ 10
#define B_ 8192
#define F_ 256
#define O_ 64
#define DK_ 5
#define NBLK 256

typedef __attribute__((ext_vector_type(8))) short short8;
typedef __attribute__((ext_vector_type(4))) float floatx4;

static __device__ __forceinline__ unsigned short f2bf(float f) {
    union { float f; unsigned u; } v; v.f = f;
    unsigned r = v.u + 0x7fffu + ((v.u >> 16) & 1u);  // round-nearest-even
    return (unsigned short)(r >> 16);
}

// One cooperative kernel, 256 blocks (1 per CU), 2 grid syncs.
// Phase A: G_part[blk][c][f] partials + xb (bf16 x)        [all 256 blocks]
// Phase B: G reduce + softmax + WT prep (swizzle-baked)    [blocks 0..39]
// Phase C: out[c][b][o] = Xbf16 @ WT[c]^T + bias via MFMA  [all 256 blocks]
__global__ __launch_bounds__(256) void fused(const float* __restrict__ x,
                                             const float* __restrict__ y,
                                             const float* __restrict__ w_key,
                                             const float* __restrict__ w_query,
                                             const float* __restrict__ w_value,
                                             const float* __restrict__ weight,
                                             const float* __restrict__ bias,
                                             float* __restrict__ G_part,
                                             unsigned short* __restrict__ xb,
                                             unsigned short* __restrict__ WT,
                                             float* __restrict__ out) {
    __shared__ float xl[32 * F_];           // 32 KiB (phase A)
    __shared__ float yl[32 * C_];
    __shared__ unsigned short wt[O_ * F_];  // 32 KiB (phase C, swizzled [o][k])
    __shared__ float red[4 * F_];           // 4 KiB (phase B)
    __shared__ float wred[4];

    cg::grid_group grid = cg::this_grid();
    const int blk = blockIdx.x;
    const int t   = threadIdx.x;

    // ================= Phase A =================
    {
        const int b0 = blk * 32;
        for (int i = t; i < 32 * C_; i += 256) yl[i] = y[b0 * C_ + i];

        const int r  = t >> 6;
        const int f4 = (t & 63) * 4;
#pragma unroll
        for (int j = 0; j < 8; ++j) {
            int row = r + 4 * j;
            float4 v = *(const float4*)(x + (size_t)(b0 + row) * F_ + f4);
            *(float4*)(xl + row * F_ + f4) = v;
            ushort4 s;
            s.x = f2bf(v.x); s.y = f2bf(v.y); s.z = f2bf(v.z); s.w = f2bf(v.w);
            *(ushort4*)(xb + (size_t)(b0 + row) * F_ + f4) = s;
        }
        __syncthreads();

        float acc[C_];
#pragma unroll
        for (int c = 0; c < C_; ++c) acc[c] = 0.f;
#pragma unroll 8
        for (int b = 0; b < 32; ++b) {
            float xv = xl[b * F_ + t];
#pragma unroll
            for (int c = 0; c < C_; ++c) acc[c] = fmaf(yl[b * C_ + c], xv, acc[c]);
        }
        float* gp = G_part + (size_t)blk * C_ * F_ + t;
#pragma unroll
        for (int c = 0; c < C_; ++c) gp[c * F_] = acc[c];
    }

    grid.sync();

    // ================= Phase B ================= (blocks 0..39)
    if (blk < C_ * 4) {
        const int c    = blk >> 2;
        const int part = blk & 3;
        const int pg   = t >> 6;   // partial-group 0..3 (wave id)
        const int fl   = t & 63;

        // sum partials p in [pg*64, pg*64+64), features {fl, fl+64, fl+128, fl+192}
        float s0 = 0.f, s1 = 0.f, s2 = 0.f, s3 = 0.f;
        const float* gp = G_part + ((size_t)(pg * 64) * C_ + c) * F_ + fl;
#pragma unroll 4
        for (int p = 0; p < 64; ++p) {
            const float* q = gp + (size_t)p * C_ * F_;   // coalesced 256B per wave
            s0 += q[0]; s1 += q[64]; s2 += q[128]; s3 += q[192];
        }
        red[pg * F_ + fl]       = s0;
        red[pg * F_ + 64 + fl]  = s1;
        red[pg * F_ + 128 + fl] = s2;
        red[pg * F_ + 192 + fl] = s3;
        __syncthreads();
        float g = (red[t] + red[F_ + t]) + (red[2 * F_ + t] + red[3 * F_ + t]);

        float s = 0.f;
#pragma unroll
        for (int k = 0; k < DK_; ++k) s += w_key[c * DK_ + k] * w_query[c * DK_ + k];

        float z = s * g * (1.0f / (float)B_);
        float m = z;
#pragma unroll
        for (int off = 32; off >= 1; off >>= 1) m = fmaxf(m, __shfl_xor(m, off));
        if ((t & 63) == 0) wred[t >> 6] = m;
        __syncthreads();   // also orders: all red[] reads above precede overwrite below
        float mm = fmaxf(fmaxf(wred[0], wred[1]), fmaxf(wred[2], wred[3]));
        red[t] = expf(z - mm) * w_value[c];   // red now holds attn2[f]
        __syncthreads();

        const int o  = t & 63;
        const int fg = t >> 6;
        const float* wsrc = weight + (size_t)c * F_ * O_;
        char* wdst = (char*)(WT + (size_t)c * O_ * F_);
#pragma unroll
        for (int gi = 0; gi < 2; ++gi) {
            int f0 = part * 64 + fg * 16 + gi * 8;
            short8 v8;
#pragma unroll
            for (int e = 0; e < 8; ++e) {
                int f = f0 + e;
                v8[e] = (short)f2bf(wsrc[f * O_ + o] * red[f]);
            }
            int byte = o * 512 + ((2 * f0) ^ ((o & 7) << 4));
            *(short8*)(wdst + byte) = v8;
        }
    }

    grid.sync();

    // ================= Phase C =================
    // Block blk lives on XCD blk%8; it only touches tiles [16*xcd, 16*xcd+16)
    // so each XCD fetches its 512 KiB xb slice once. 5 units/block, c-major
    // within the XCD so WT re-stages <= 2x per block.
    {
        const int xcd  = blk & 7;
        const int slot = blk >> 3;          // 0..31
        const int w  = t >> 6;
        const int l  = t & 63;
        const int lr = l & 15;
        const int lg = l >> 4;
        int last_c = -1;

        for (int i = 0; i < 5; ++i) {
            int ul   = slot * 5 + i;        // 0..159: [c 0..9][tile_off 0..15]
            int c    = ul >> 4;
            int tile = xcd * 16 + (ul & 15);
            int b0   = tile * 64;

            if (c != last_c) {
                __syncthreads();
                const short8* src = (const short8*)(WT + (size_t)c * O_ * F_);
                short8* dst = (short8*)wt;
#pragma unroll
                for (int j = 0; j < 8; ++j) dst[t + 256 * j] = src[t + 256 * j];
                __syncthreads();
                last_c = c;
            }

            const unsigned short* xrow = xb + (size_t)(b0 + w * 16 + lr) * F_;
            short8 a[8];
#pragma unroll
            for (int k0 = 0; k0 < 8; ++k0)
                a[k0] = *(const short8*)(xrow + k0 * 32 + lg * 8);

            floatx4 acc[4];
#pragma unroll
            for (int n = 0; n < 4; ++n) {
                float bo = bias[c * O_ + n * 16 + lr];
                acc[n] = (floatx4){bo, bo, bo, bo};
            }
#pragma unroll
            for (int k0 = 0; k0 < 8; ++k0) {
#pragma unroll
                for (int n = 0; n < 4; ++n) {
                    int o = n * 16 + lr;
                    int byte = o * 512 + ((k0 * 64 + lg * 16) ^ ((o & 7) << 4));
                    short8 bf = *(const short8*)((const char*)wt + byte);
                    acc[n] = __builtin_amdgcn_mfma_f32_16x16x32_bf16(a[k0], bf, acc[n], 0, 0, 0);
                }
            }
#pragma unroll
            for (int n = 0; n < 4; ++n) {
                int col = n * 16 + lr;
#pragma unroll
                for (int r2 = 0; r2 < 4; ++r2) {
                    int row = b0 + w * 16 + lg * 4 + r2;
                    out[((size_t)c * B_ + row) * O_ + col] = acc[n][r2];
                }
            }
        }
    }
}

extern "C" void kernel_launch(void* const* d_in, const int* in_sizes, int n_in,
                              void* d_out, int out_size, void* d_ws, size_t ws_size,
                              hipStream_t stream) {
    const float* x       = (const float*)d_in[0];
    const float* y       = (const float*)d_in[1];
    const float* w_key   = (const float*)d_in[2];
    const float* w_query = (const float*)d_in[3];
    const float* w_value = (const float*)d_in[4];
    const float* weight  = (const float*)d_in[5];
    const float* bias    = (const float*)d_in[6];
    float* out = (float*)d_out;

    char* ws = (char*)d_ws;
    unsigned short* xb     = (unsigned short*)ws;                              // 4 MiB
    unsigned short* WT     = (unsigned short*)(ws + (size_t)B_ * F_ * 2);      // 320 KiB
    float*          G_part = (float*)(ws + (size_t)B_ * F_ * 2 + C_ * O_ * F_ * 2);  // 2.62 MiB

    void* args[] = {(void*)&x, (void*)&y, (void*)&w_key, (void*)&w_query,
                    (void*)&w_value, (void*)&weight, (void*)&bias,
                    (void*)&G_part, (void*)&xb, (void*)&WT, (void*)&out};
    hipLaunchCooperativeKernel((const void*)fused, dim3(NBLK), dim3(256),
                               args, 0, stream);
}

// Round 7
// 31.918 us; speedup vs baseline: 2.9725x; 2.9725x over previous
//
#include <hip/hip_runtime.h>
#include <hip/hip_bf16.h>

#define C_ 10
#define B_ 8192
#define F_ 256
#define O_ 64
#define DK_ 5
#define NBLK1 256   // k1 blocks -> partial count

typedef __attribute__((ext_vector_type(8))) short short8;
typedef __attribute__((ext_vector_type(4))) float floatx4;

static __device__ __forceinline__ unsigned short f2bf(float f) {
    union { float f; unsigned u; } v; v.f = f;
    unsigned r = v.u + 0x7fffu + ((v.u >> 16) & 1u);  // round-nearest-even
    return (unsigned short)(r >> 16);
}

// ---------------- K1: per-block partial G + emit x as bf16 ------------------
// G_part[blk][c][f] = sum_{b in block} x[b,f]*y[b,c]   (no atomics, no memset)
__global__ __launch_bounds__(256) void k1_reduce(const float* __restrict__ x,
                                                 const float* __restrict__ y,
                                                 float* __restrict__ G_part,
                                                 unsigned short* __restrict__ xb) {
    __shared__ float xl[32 * F_];      // 32 KiB
    __shared__ float yl[32 * C_];
    const int b0 = blockIdx.x * 32;
    const int t  = threadIdx.x;

    for (int i = t; i < 32 * C_; i += 256) yl[i] = y[b0 * C_ + i];

    const int r  = t >> 6;             // row sub-slot 0..3
    const int f4 = (t & 63) * 4;       // 4 features per thread
#pragma unroll
    for (int j = 0; j < 8; ++j) {
        int row = r + 4 * j;           // 0..31
        float4 v = *(const float4*)(x + (size_t)(b0 + row) * F_ + f4);
        *(float4*)(xl + row * F_ + f4) = v;
        ushort4 s;
        s.x = f2bf(v.x); s.y = f2bf(v.y); s.z = f2bf(v.z); s.w = f2bf(v.w);
        *(ushort4*)(xb + (size_t)(b0 + row) * F_ + f4) = s;
    }
    __syncthreads();

    float acc[C_];
#pragma unroll
    for (int c = 0; c < C_; ++c) acc[c] = 0.f;

#pragma unroll 8
    for (int b = 0; b < 32; ++b) {
        float xv = xl[b * F_ + t];     // 2-way bank alias (free)
#pragma unroll
        for (int c = 0; c < C_; ++c) acc[c] = fmaf(yl[b * C_ + c], xv, acc[c]);
    }

    float* gp = G_part + (size_t)blockIdx.x * C_ * F_ + t;
#pragma unroll
    for (int c = 0; c < C_; ++c) gp[c * F_] = acc[c];   // coalesced, non-atomic
}

// ---------------- K2: wave-parallel fan-in + softmax + weight prep ----------
// 4 blocks per c. Each of 4 waves sums 64 partials (coalesced 256B rows,
// all loads independent), LDS tree combine, softmax, then WT prep.
// WT[c] swizzle-baked bf16 [o][k=f]: byte(o,f) = o*512 + ((2f) ^ ((o&7)<<4))
__global__ __launch_bounds__(256) void k2_wprep(const float* __restrict__ G_part,
                                                const float* __restrict__ w_key,
                                                const float* __restrict__ w_query,
                                                const float* __restrict__ w_value,
                                                const float* __restrict__ weight,
                                                unsigned short* __restrict__ WT) {
    __shared__ float red[4 * F_];      // 4 KiB
    __shared__ float wred[4];
    const int c    = blockIdx.x >> 2;
    const int part = blockIdx.x & 3;   // 64 features each for the prep phase
    const int t    = threadIdx.x;
    const int pg   = t >> 6;           // wave id = partial-group 0..3
    const int fl   = t & 63;

    // wave pg sums partials [pg*64, pg*64+64) for features fl+{0,64,128,192}
    float s0 = 0.f, s1 = 0.f, s2 = 0.f, s3 = 0.f;
    const float* gp = G_part + ((size_t)(pg * 64) * C_ + c) * F_ + fl;
#pragma unroll 4
    for (int p = 0; p < 64; ++p) {
        const float* q = gp + (size_t)p * C_ * F_;   // coalesced, independent
        s0 += q[0]; s1 += q[64]; s2 += q[128]; s3 += q[192];
    }
    red[pg * F_ + fl]       = s0;
    red[pg * F_ + 64 + fl]  = s1;
    red[pg * F_ + 128 + fl] = s2;
    red[pg * F_ + 192 + fl] = s3;
    __syncthreads();
    float g = (red[t] + red[F_ + t]) + (red[2 * F_ + t] + red[3 * F_ + t]);

    float s = 0.f;
#pragma unroll
    for (int k = 0; k < DK_; ++k) s += w_key[c * DK_ + k] * w_query[c * DK_ + k];

    float z = s * g * (1.0f / (float)B_);
    float m = z;
#pragma unroll
    for (int off = 32; off >= 1; off >>= 1) m = fmaxf(m, __shfl_xor(m, off));
    if ((t & 63) == 0) wred[t >> 6] = m;
    __syncthreads();
    float mm = fmaxf(fmaxf(wred[0], wred[1]), fmaxf(wred[2], wred[3]));
    __syncthreads();                   // all reads of red[] done before overwrite
    red[t] = expf(z - mm) * w_value[c];   // red[0..255] now holds attn2[f]
    __syncthreads();

    const int o  = t & 63;
    const int fg = t >> 6;
    const float* wsrc = weight + (size_t)c * F_ * O_;
    char* wdst = (char*)(WT + (size_t)c * O_ * F_);
#pragma unroll
    for (int gi = 0; gi < 2; ++gi) {
        int f0 = part * 64 + fg * 16 + gi * 8;
        short8 v8;
#pragma unroll
        for (int e = 0; e < 8; ++e) {
            int f = f0 + e;
            v8[e] = (short)f2bf(wsrc[f * O_ + o] * red[f]);  // coalesced along o
        }
        int byte = o * 512 + ((2 * f0) ^ ((o & 7) << 4));    // 16B-aligned
        *(short8*)(wdst + byte) = v8;
    }
}

// ---------------- K3: out[c][b][o] = Xbf16 @ WT[c]^T + bias, MFMA 16x16x32 ---
// 64-row tiles, 4 waves x 16 rows, A prefetched to regs before staging barrier
__global__ __launch_bounds__(256) void k3_mfma(const unsigned short* __restrict__ xb,
                                               const unsigned short* __restrict__ WT,
                                               const float* __restrict__ bias,
                                               float* __restrict__ out) {
    __shared__ unsigned short wt[O_ * F_];  // 32 KiB swizzled [o][k]
    const int c  = blockIdx.y;
    const int b0 = blockIdx.x * 64;
    const int t  = threadIdx.x;
    const int w  = t >> 6;
    const int l  = t & 63;
    const int lr = l & 15;
    const int lg = l >> 4;

    // A prefetch: 8 x short8 (row b0+w*16+lr, k = k0*32 + lg*8), issues early
    const unsigned short* xrow = xb + (size_t)(b0 + w * 16 + lr) * F_;
    short8 a[8];
#pragma unroll
    for (int k0 = 0; k0 < 8; ++k0) a[k0] = *(const short8*)(xrow + k0 * 32 + lg * 8);

    // stage WT[c] linearly (swizzle pre-baked)
    {
        const short8* src = (const short8*)(WT + (size_t)c * O_ * F_);
        short8* dst = (short8*)wt;
#pragma unroll
        for (int j = 0; j < 8; ++j) dst[t + 256 * j] = src[t + 256 * j];
    }
    __syncthreads();

    floatx4 acc[4];
#pragma unroll
    for (int n = 0; n < 4; ++n) {
        float bo = bias[c * O_ + n * 16 + lr];
        acc[n] = (floatx4){bo, bo, bo, bo};   // bias folded into C-init
    }

#pragma unroll
    for (int k0 = 0; k0 < 8; ++k0) {
#pragma unroll
        for (int n = 0; n < 4; ++n) {
            int o = n * 16 + lr;
            int byte = o * 512 + ((k0 * 64 + lg * 16) ^ ((o & 7) << 4));
            short8 bf = *(const short8*)((const char*)wt + byte);  // conflict-free
            acc[n] = __builtin_amdgcn_mfma_f32_16x16x32_bf16(a[k0], bf, acc[n], 0, 0, 0);
        }
    }

    // D layout: col = lane&15, row = (lane>>4)*4 + reg
#pragma unroll
    for (int n = 0; n < 4; ++n) {
        int col = n * 16 + lr;
#pragma unroll
        for (int r = 0; r < 4; ++r) {
            int row = b0 + w * 16 + lg * 4 + r;
            out[((size_t)c * B_ + row) * O_ + col] = acc[n][r];
        }
    }
}

extern "C" void kernel_launch(void* const* d_in, const int* in_sizes, int n_in,
                              void* d_out, int out_size, void* d_ws, size_t ws_size,
                              hipStream_t stream) {
    const float* x       = (const float*)d_in[0];
    const float* y       = (const float*)d_in[1];
    const float* w_key   = (const float*)d_in[2];
    const float* w_query = (const float*)d_in[3];
    const float* w_value = (const float*)d_in[4];
    const float* weight  = (const float*)d_in[5];
    const float* bias    = (const float*)d_in[6];
    float* out = (float*)d_out;

    char* ws = (char*)d_ws;
    unsigned short* xb     = (unsigned short*)ws;                                  // 4 MiB
    unsigned short* WT     = (unsigned short*)(ws + (size_t)B_ * F_ * 2);          // 320 KiB
    float*          G_part = (float*)(ws + (size_t)B_ * F_ * 2 + C_ * O_ * F_ * 2);// 2.62 MiB

    k1_reduce<<<NBLK1, 256, 0, stream>>>(x, y, G_part, xb);
    k2_wprep<<<C_ * 4, 256, 0, stream>>>(G_part, w_key, w_query, w_value, weight, WT);
    dim3 g3(B_ / 64, C_);
    k3_mfma<<<g3, 256, 0, stream>>>(xb, WT, bias, out);
}

// Round 8
// 28.756 us; speedup vs baseline: 3.2994x; 1.1100x over previous
//
#include <hip/hip_runtime.h>
#include <hip/hip_bf16.h>

#define C_ 10
#define B_ 8192
#define F_ 256
#define O_ 64
#define DK_ 5
#define NBLK1 512   // k1 blocks -> partial count (16 rows each)
#define NG2   16    // second-level partial count

typedef __attribute__((ext_vector_type(8))) short short8;
typedef __attribute__((ext_vector_type(4))) float floatx4;

static __device__ __forceinline__ unsigned short f2bf(float f) {
    union { float f; unsigned u; } v; v.f = f;
    unsigned r = v.u + 0x7fffu + ((v.u >> 16) & 1u);  // round-nearest-even
    return (unsigned short)(r >> 16);
}

// ---------------- K1: per-block partial G + emit x as bf16 ------------------
// 512 blocks x 16 rows: 2 blocks/CU -> 2 waves/SIMD for latency hiding.
// G_part[blk][c][f] = sum_{b in block} x[b,f]*y[b,c]
__global__ __launch_bounds__(256) void k1_reduce(const float* __restrict__ x,
                                                 const float* __restrict__ y,
                                                 float* __restrict__ G_part,
                                                 unsigned short* __restrict__ xb) {
    __shared__ float xl[16 * F_];      // 16 KiB
    __shared__ float yl[16 * C_];
    const int b0 = blockIdx.x * 16;
    const int t  = threadIdx.x;

    for (int i = t; i < 16 * C_; i += 256) yl[i] = y[b0 * C_ + i];

#pragma unroll
    for (int j = 0; j < 4; ++j) {
        int i4  = t + 256 * j;         // float4 index, 1024 total
        int row = i4 >> 6;             // 64 float4 per row
        int f4  = (i4 & 63) * 4;
        float4 v = *(const float4*)(x + (size_t)(b0 + row) * F_ + f4);
        *(float4*)(xl + row * F_ + f4) = v;
        ushort4 s;
        s.x = f2bf(v.x); s.y = f2bf(v.y); s.z = f2bf(v.z); s.w = f2bf(v.w);
        *(ushort4*)(xb + (size_t)(b0 + row) * F_ + f4) = s;
    }
    __syncthreads();

    float acc[C_];
#pragma unroll
    for (int c = 0; c < C_; ++c) acc[c] = 0.f;

#pragma unroll
    for (int b = 0; b < 16; ++b) {
        float xv = xl[b * F_ + t];     // 2-way bank alias (free)
#pragma unroll
        for (int c = 0; c < C_; ++c) acc[c] = fmaf(yl[b * C_ + c], xv, acc[c]);
    }

    float* gp = G_part + (size_t)blockIdx.x * C_ * F_ + t;
#pragma unroll
    for (int c = 0; c < C_; ++c) gp[c * F_] = acc[c];   // coalesced, non-atomic
}

// ---------------- K1b: tree fan-in, 32 partials per block, coalesced --------
// G2[g][c][f] = sum_{i<32} G_part[g*32+i][c][f];  grid = C_*NG2 = 160 blocks
__global__ __launch_bounds__(256) void k1b_reduce(const float* __restrict__ G_part,
                                                  float* __restrict__ G2) {
    const int c = (int)blockIdx.x >> 4;
    const int g = (int)blockIdx.x & 15;
    const int t = threadIdx.x;
    const float* gp = G_part + (size_t)(g * 32) * C_ * F_ + c * F_ + t;
    float a0 = 0.f, a1 = 0.f, a2 = 0.f, a3 = 0.f;
#pragma unroll
    for (int i = 0; i < 32; i += 4) {   // 32 independent coalesced 1KB-row loads
        a0 += gp[(size_t)(i + 0) * C_ * F_];
        a1 += gp[(size_t)(i + 1) * C_ * F_];
        a2 += gp[(size_t)(i + 2) * C_ * F_];
        a3 += gp[(size_t)(i + 3) * C_ * F_];
    }
    G2[(size_t)g * C_ * F_ + c * F_ + t] = (a0 + a1) + (a2 + a3);
}

// ---------------- K2: final reduce + softmax + weight prep. 4 blocks per c --
// attn2[f] = exp(z-zmax)*w_value[c] (redundant per block);
// WT[c] swizzle-baked bf16 [o][k=f]: byte(o,f) = o*512 + ((2f) ^ ((o&7)<<4))
__global__ __launch_bounds__(256) void k2_wprep(const float* __restrict__ G2,
                                                const float* __restrict__ w_key,
                                                const float* __restrict__ w_query,
                                                const float* __restrict__ w_value,
                                                const float* __restrict__ weight,
                                                unsigned short* __restrict__ WT) {
    __shared__ float a2[F_];
    __shared__ float wred[4];
    const int c    = blockIdx.x >> 2;
    const int part = blockIdx.x & 3;   // 64 features each for the prep phase
    const int t    = threadIdx.x;

    // sum the 16 second-level partials for (c, f=t): coalesced, fully parallel
    const float* gp = G2 + c * F_ + t;
    float g0 = 0.f, g1 = 0.f, g2 = 0.f, g3 = 0.f;
#pragma unroll
    for (int i = 0; i < NG2; i += 4) {
        g0 += gp[(size_t)(i + 0) * C_ * F_];
        g1 += gp[(size_t)(i + 1) * C_ * F_];
        g2 += gp[(size_t)(i + 2) * C_ * F_];
        g3 += gp[(size_t)(i + 3) * C_ * F_];
    }
    float g = (g0 + g1) + (g2 + g3);

    float s = 0.f;
#pragma unroll
    for (int k = 0; k < DK_; ++k) s += w_key[c * DK_ + k] * w_query[c * DK_ + k];

    float z = s * g * (1.0f / (float)B_);
    float m = z;
#pragma unroll
    for (int off = 32; off >= 1; off >>= 1) m = fmaxf(m, __shfl_xor(m, off));
    if ((t & 63) == 0) wred[t >> 6] = m;
    __syncthreads();
    float mm = fmaxf(fmaxf(wred[0], wred[1]), fmaxf(wred[2], wred[3]));
    a2[t] = expf(z - mm) * w_value[c];
    __syncthreads();

    const int o  = t & 63;
    const int fg = t >> 6;
    const float* wsrc = weight + (size_t)c * F_ * O_;
    char* wdst = (char*)(WT + (size_t)c * O_ * F_);
#pragma unroll
    for (int gi = 0; gi < 2; ++gi) {
        int f0 = part * 64 + fg * 16 + gi * 8;
        short8 v8;
#pragma unroll
        for (int e = 0; e < 8; ++e) {
            int f = f0 + e;
            v8[e] = (short)f2bf(wsrc[f * O_ + o] * a2[f]);  // coalesced along o
        }
        int byte = o * 512 + ((2 * f0) ^ ((o & 7) << 4));   // 16B-aligned
        *(short8*)(wdst + byte) = v8;
    }
}

// ---------------- K3: out[c][b][o] = Xbf16 @ WT[c]^T + bias, MFMA 16x16x32 ---
// 64-row tiles, 4 waves x 16 rows, A prefetched to regs before staging barrier
__global__ __launch_bounds__(256) void k3_mfma(const unsigned short* __restrict__ xb,
                                               const unsigned short* __restrict__ WT,
                                               const float* __restrict__ bias,
                                               float* __restrict__ out) {
    __shared__ unsigned short wt[O_ * F_];  // 32 KiB swizzled [o][k]
    const int c  = blockIdx.y;
    const int b0 = blockIdx.x * 64;
    const int t  = threadIdx.x;
    const int w  = t >> 6;
    const int l  = t & 63;
    const int lr = l & 15;
    const int lg = l >> 4;

    // A prefetch: 8 x short8 (row b0+w*16+lr, k = k0*32 + lg*8), issues early
    const unsigned short* xrow = xb + (size_t)(b0 + w * 16 + lr) * F_;
    short8 a[8];
#pragma unroll
    for (int k0 = 0; k0 < 8; ++k0) a[k0] = *(const short8*)(xrow + k0 * 32 + lg * 8);

    // stage WT[c] linearly (swizzle pre-baked)
    {
        const short8* src = (const short8*)(WT + (size_t)c * O_ * F_);
        short8* dst = (short8*)wt;
#pragma unroll
        for (int j = 0; j < 8; ++j) dst[t + 256 * j] = src[t + 256 * j];
    }
    __syncthreads();

    floatx4 acc[4];
#pragma unroll
    for (int n = 0; n < 4; ++n) {
        float bo = bias[c * O_ + n * 16 + lr];
        acc[n] = (floatx4){bo, bo, bo, bo};   // bias folded into C-init
    }

#pragma unroll
    for (int k0 = 0; k0 < 8; ++k0) {
#pragma unroll
        for (int n = 0; n < 4; ++n) {
            int o = n * 16 + lr;
            int byte = o * 512 + ((k0 * 64 + lg * 16) ^ ((o & 7) << 4));
            short8 bf = *(const short8*)((const char*)wt + byte);  // conflict-free
            acc[n] = __builtin_amdgcn_mfma_f32_16x16x32_bf16(a[k0], bf, acc[n], 0, 0, 0);
        }
    }

    // D layout: col = lane&15, row = (lane>>4)*4 + reg
#pragma unroll
    for (int n = 0; n < 4; ++n) {
        int col = n * 16 + lr;
#pragma unroll
        for (int r = 0; r < 4; ++r) {
            int row = b0 + w * 16 + lg * 4 + r;
            out[((size_t)c * B_ + row) * O_ + col] = acc[n][r];
        }
    }
}

extern "C" void kernel_launch(void* const* d_in, const int* in_sizes, int n_in,
                              void* d_out, int out_size, void* d_ws, size_t ws_size,
                              hipStream_t stream) {
    const float* x       = (const float*)d_in[0];
    const float* y       = (const float*)d_in[1];
    const float* w_key   = (const float*)d_in[2];
    const float* w_query = (const float*)d_in[3];
    const float* w_value = (const float*)d_in[4];
    const float* weight  = (const float*)d_in[5];
    const float* bias    = (const float*)d_in[6];
    float* out = (float*)d_out;

    char* ws = (char*)d_ws;
    unsigned short* xb     = (unsigned short*)ws;                                   // 4 MiB
    unsigned short* WT     = (unsigned short*)(ws + (size_t)B_ * F_ * 2);           // 320 KiB
    float*          G_part = (float*)(ws + (size_t)B_ * F_ * 2 + C_ * O_ * F_ * 2); // 5.24 MiB
    float*          G2     = G_part + (size_t)NBLK1 * C_ * F_;                      // 160 KiB

    k1_reduce<<<NBLK1, 256, 0, stream>>>(x, y, G_part, xb);
    k1b_reduce<<<C_ * NG2, 256, 0, stream>>>(G_part, G2);
    k2_wprep<<<C_ * 4, 256, 0, stream>>>(G2, w_key, w_query, w_value, weight, WT);
    dim3 g3(B_ / 64, C_);
    k3_mfma<<<g3, 256, 0, stream>>>(xb, WT, bias, out);
}

// Round 9
// 28.525 us; speedup vs baseline: 3.3261x; 1.0081x over previous
//
#include <hip/hip_runtime.h>
#include <hip/hip_bf16.h>

#define C_ 10
#define B_ 8192
#define F_ 256
#define O_ 64
#define DK_ 5
#define NBLK1 256   // k1 blocks -> partial count (32 rows each)
#define NG2   16    // second-level partial count

typedef __attribute__((ext_vector_type(8))) short short8;
typedef __attribute__((ext_vector_type(4))) float floatx4;

static __device__ __forceinline__ unsigned short f2bf(float f) {
    union { float f; unsigned u; } v; v.f = f;
    unsigned r = v.u + 0x7fffu + ((v.u >> 16) & 1u);  // round-nearest-even
    return (unsigned short)(r >> 16);
}

// ---------------- K1: per-block partial G + emit x as bf16 ------------------
// G_part[blk][c][f] = sum_{b in block} x[b,f]*y[b,c]   (no atomics, no memset)
__global__ __launch_bounds__(256) void k1_reduce(const float* __restrict__ x,
                                                 const float* __restrict__ y,
                                                 float* __restrict__ G_part,
                                                 unsigned short* __restrict__ xb) {
    __shared__ float xl[32 * F_];      // 32 KiB
    __shared__ float yl[32 * C_];
    const int b0 = blockIdx.x * 32;
    const int t  = threadIdx.x;

    for (int i = t; i < 32 * C_; i += 256) yl[i] = y[b0 * C_ + i];

    const int r  = t >> 6;             // row sub-slot 0..3
    const int f4 = (t & 63) * 4;       // 4 features per thread
#pragma unroll
    for (int j = 0; j < 8; ++j) {
        int row = r + 4 * j;           // 0..31
        float4 v = *(const float4*)(x + (size_t)(b0 + row) * F_ + f4);
        *(float4*)(xl + row * F_ + f4) = v;
        ushort4 s;
        s.x = f2bf(v.x); s.y = f2bf(v.y); s.z = f2bf(v.z); s.w = f2bf(v.w);
        *(ushort4*)(xb + (size_t)(b0 + row) * F_ + f4) = s;
    }
    __syncthreads();

    float acc[C_];
#pragma unroll
    for (int c = 0; c < C_; ++c) acc[c] = 0.f;

#pragma unroll 8
    for (int b = 0; b < 32; ++b) {
        float xv = xl[b * F_ + t];     // 2-way bank alias (free)
#pragma unroll
        for (int c = 0; c < C_; ++c) acc[c] = fmaf(yl[b * C_ + c], xv, acc[c]);
    }

    float* gp = G_part + (size_t)blockIdx.x * C_ * F_ + t;
#pragma unroll
    for (int c = 0; c < C_; ++c) gp[c * F_] = acc[c];   // coalesced, non-atomic
}

// ---------------- K1b: tree fan-in, 16 partials per block, coalesced --------
// G2[g][c][f] = sum_{i<16} G_part[g*16+i][c][f];  grid = C_*NG2 = 160 blocks
__global__ __launch_bounds__(256) void k1b_reduce(const float* __restrict__ G_part,
                                                  float* __restrict__ G2) {
    const int c = (int)blockIdx.x >> 4;
    const int g = (int)blockIdx.x & 15;
    const int t = threadIdx.x;
    const float* gp = G_part + (size_t)(g * 16) * C_ * F_ + c * F_ + t;
    float a0 = 0.f, a1 = 0.f, a2 = 0.f, a3 = 0.f;
#pragma unroll
    for (int i = 0; i < 16; i += 4) {   // 16 independent coalesced 1KB-row loads
        a0 += gp[(size_t)(i + 0) * C_ * F_];
        a1 += gp[(size_t)(i + 1) * C_ * F_];
        a2 += gp[(size_t)(i + 2) * C_ * F_];
        a3 += gp[(size_t)(i + 3) * C_ * F_];
    }
    G2[(size_t)g * C_ * F_ + c * F_ + t] = (a0 + a1) + (a2 + a3);
}

// ---------------- K3: fused softmax + weight-prep + MFMA GEMM ---------------
// Per block: reduce G2 (16 loads), softmax -> a2[] in LDS, scale weight[c] to
// bf16 directly into swizzled LDS, then out = Xbf16 @ wt^T + bias via MFMA.
// Swizzle: byte(o,f) = o*512 + ((2f) ^ ((o&7)<<4))
__global__ __launch_bounds__(256) void k3_fused(const unsigned short* __restrict__ xb,
                                                const float* __restrict__ G2,
                                                const float* __restrict__ w_key,
                                                const float* __restrict__ w_query,
                                                const float* __restrict__ w_value,
                                                const float* __restrict__ weight,
                                                const float* __restrict__ bias,
                                                float* __restrict__ out) {
    __shared__ unsigned short wt[O_ * F_];  // 32 KiB swizzled [o][k]
    __shared__ float a2[F_];
    __shared__ float wred[4];
    const int c  = blockIdx.y;
    const int b0 = blockIdx.x * 64;
    const int t  = threadIdx.x;
    const int w  = t >> 6;
    const int l  = t & 63;
    const int lr = l & 15;
    const int lg = l >> 4;

    // A prefetch FIRST: 8 x short8 global loads overlap the prep below
    const unsigned short* xrow = xb + (size_t)(b0 + w * 16 + lr) * F_;
    short8 a[8];
#pragma unroll
    for (int k0 = 0; k0 < 8; ++k0) a[k0] = *(const short8*)(xrow + k0 * 32 + lg * 8);

    // ---- G2 reduce for (c, f=t): 16 coalesced, independent, L2-hot loads ----
    {
        const float* gp = G2 + c * F_ + t;
        float g0 = 0.f, g1 = 0.f, g2 = 0.f, g3 = 0.f;
#pragma unroll
        for (int i = 0; i < NG2; i += 4) {
            g0 += gp[(size_t)(i + 0) * C_ * F_];
            g1 += gp[(size_t)(i + 1) * C_ * F_];
            g2 += gp[(size_t)(i + 2) * C_ * F_];
            g3 += gp[(size_t)(i + 3) * C_ * F_];
        }
        float g = (g0 + g1) + (g2 + g3);

        float s = 0.f;
#pragma unroll
        for (int k = 0; k < DK_; ++k) s += w_key[c * DK_ + k] * w_query[c * DK_ + k];

        float z = s * g * (1.0f / (float)B_);
        float m = z;
#pragma unroll
        for (int off = 32; off >= 1; off >>= 1) m = fmaxf(m, __shfl_xor(m, off));
        if ((t & 63) == 0) wred[t >> 6] = m;
        __syncthreads();
        float mm = fmaxf(fmaxf(wred[0], wred[1]), fmaxf(wred[2], wred[3]));
        a2[t] = expf(z - mm) * w_value[c];
        __syncthreads();
    }

    // ---- weight prep straight into swizzled LDS (no global WT) ----
    // thread (o=l, fg=w) covers f0 = gi*32 + fg*8, gi = 0..7
    {
        const float* wsrc = weight + (size_t)c * F_ * O_;
#pragma unroll
        for (int gi = 0; gi < 8; ++gi) {
            int f0 = gi * 32 + w * 8;
            short8 v8;
#pragma unroll
            for (int e = 0; e < 8; ++e) {
                int f = f0 + e;
                v8[e] = (short)f2bf(wsrc[f * O_ + l] * a2[f]);  // coalesced along o
            }
            int byte = l * 512 + ((2 * f0) ^ ((l & 7) << 4));
            *(short8*)((char*)wt + byte) = v8;
        }
    }
    __syncthreads();

    floatx4 acc[4];
#pragma unroll
    for (int n = 0; n < 4; ++n) {
        float bo = bias[c * O_ + n * 16 + lr];
        acc[n] = (floatx4){bo, bo, bo, bo};   // bias folded into C-init
    }

#pragma unroll
    for (int k0 = 0; k0 < 8; ++k0) {
#pragma unroll
        for (int n = 0; n < 4; ++n) {
            int o = n * 16 + lr;
            int byte = o * 512 + ((k0 * 64 + lg * 16) ^ ((o & 7) << 4));
            short8 bf = *(const short8*)((const char*)wt + byte);  // conflict-free
            acc[n] = __builtin_amdgcn_mfma_f32_16x16x32_bf16(a[k0], bf, acc[n], 0, 0, 0);
        }
    }

    // D layout: col = lane&15, row = (lane>>4)*4 + reg
#pragma unroll
    for (int n = 0; n < 4; ++n) {
        int col = n * 16 + lr;
#pragma unroll
        for (int r = 0; r < 4; ++r) {
            int row = b0 + w * 16 + lg * 4 + r;
            out[((size_t)c * B_ + row) * O_ + col] = acc[n][r];
        }
    }
}

extern "C" void kernel_launch(void* const* d_in, const int* in_sizes, int n_in,
                              void* d_out, int out_size, void* d_ws, size_t ws_size,
                              hipStream_t stream) {
    const float* x       = (const float*)d_in[0];
    const float* y       = (const float*)d_in[1];
    const float* w_key   = (const float*)d_in[2];
    const float* w_query = (const float*)d_in[3];
    const float* w_value = (const float*)d_in[4];
    const float* weight  = (const float*)d_in[5];
    const float* bias    = (const float*)d_in[6];
    float* out = (float*)d_out;

    char* ws = (char*)d_ws;
    unsigned short* xb     = (unsigned short*)ws;                 // 4 MiB
    float*          G_part = (float*)(ws + (size_t)B_ * F_ * 2);  // 2.62 MiB
    float*          G2     = G_part + (size_t)NBLK1 * C_ * F_;    // 160 KiB

    k1_reduce<<<NBLK1, 256, 0, stream>>>(x, y, G_part, xb);
    k1b_reduce<<<C_ * NG2, 256, 0, stream>>>(G_part, G2);
    dim3 g3(B_ / 64, C_);
    k3_fused<<<g3, 256, 0, stream>>>(xb, G2, w_key, w_query, w_value, weight, bias, out);
}